// Round 1
// baseline (1122.833 us; speedup 1.0000x reference)
//
#include <hip/hip_runtime.h>

constexpr int NPIX = 196608;
constexpr int FF   = 32;   // features
// acc layout: [n][f][2] (f*2+d), matches reshape(F*DM) with d fastest

// ---------------- Chebyshev init: T1 = L(x); acc = x*wd[0] + T1*wd[1] ----------------
template<int NB>
__global__ __launch_bounds__(256) void cheb_init_kernel(
    const float* __restrict__ x,
    const int*   __restrict__ idx,
    const float* __restrict__ wnb,
    const float* __restrict__ wd,   // [K][F][2]
    float* __restrict__ T1,
    float* __restrict__ acc)
{
    int t = blockIdx.x * 256 + threadIdx.x;
    int n = t >> 5;
    int f = t & 31;

    const int4*   ip  = reinterpret_cast<const int4*>(idx + (size_t)n * NB);
    const float4* wp4 = reinterpret_cast<const float4*>(wnb + (size_t)n * NB);

    float s = 0.f;
#pragma unroll
    for (int j4 = 0; j4 < NB / 4; ++j4) {
        int4   i4 = ip[j4];
        float4 w4 = wp4[j4];
        s += w4.x * x[i4.x * FF + f];
        s += w4.y * x[i4.y * FF + f];
        s += w4.z * x[i4.z * FF + f];
        s += w4.w * x[i4.w * FF + f];
    }
    int base = n * FF + f;
    T1[base] = s;
    float x0 = x[base];
    float2 wd0 = *reinterpret_cast<const float2*>(wd + f * 2);
    float2 wd1 = *reinterpret_cast<const float2*>(wd + (FF + f) * 2);
    float2 a;
    a.x = x0 * wd0.x + s * wd1.x;
    a.y = x0 * wd0.y + s * wd1.y;
    *reinterpret_cast<float2*>(acc + (size_t)n * (2 * FF) + f * 2) = a;
}

// ------------- Chebyshev step: Tnew = 2*L(Tprev) - Told; acc += Tnew*wd[k] -------------
// Told may alias Tout (in-place safe: each thread touches only its own element).
template<int NB>
__global__ __launch_bounds__(256) void cheb_step_kernel(
    const float* __restrict__ Tprev,
    const float* __restrict__ Told,
    float*       __restrict__ Tout,
    const int*   __restrict__ idx,
    const float* __restrict__ wnb,
    const float* __restrict__ wd,   // [K][F][2]
    int k,
    float* __restrict__ acc)
{
    int t = blockIdx.x * 256 + threadIdx.x;
    int n = t >> 5;
    int f = t & 31;

    const int4*   ip  = reinterpret_cast<const int4*>(idx + (size_t)n * NB);
    const float4* wp4 = reinterpret_cast<const float4*>(wnb + (size_t)n * NB);

    float s = 0.f;
#pragma unroll
    for (int j4 = 0; j4 < NB / 4; ++j4) {
        int4   i4 = ip[j4];
        float4 w4 = wp4[j4];
        s += w4.x * Tprev[i4.x * FF + f];
        s += w4.y * Tprev[i4.y * FF + f];
        s += w4.z * Tprev[i4.z * FF + f];
        s += w4.w * Tprev[i4.w * FF + f];
    }
    int base = n * FF + f;
    float tn = 2.f * s - Told[base];
    Tout[base] = tn;

    float2 wdk = *reinterpret_cast<const float2*>(wd + (k * FF + f) * 2);
    float2* ap = reinterpret_cast<float2*>(acc + (size_t)n * (2 * FF) + f * 2);
    float2 a = *ap;
    a.x += tn * wdk.x;
    a.y += tn * wdk.y;
    *ap = a;
}

// ----- finish: z = acc @ wp + b; relu; layernorm(gamma,beta); optional +residual -----
template<bool RESIDUAL>
__global__ __launch_bounds__(256) void finish_kernel(
    const float* __restrict__ acc,   // [N][64]
    const float* __restrict__ wp,    // [64][32]
    const float* __restrict__ bias,  // [32]
    const float* __restrict__ gamma,
    const float* __restrict__ beta,
    const float* __restrict__ resid, // maps (layer2) or nullptr
    float* __restrict__ out)         // [N][32]
{
    __shared__ float swp[64 * 32];
    __shared__ float sacc[8 * 64];

    int tid = threadIdx.x;
    for (int i = tid; i < 64 * 32; i += 256) swp[i] = wp[i];
    int n0 = blockIdx.x * 8;
    for (int i = tid; i < 8 * 64; i += 256) sacc[i] = acc[(size_t)n0 * 64 + i];
    __syncthreads();

    int n = tid >> 5;   // 0..7 within block
    int g = tid & 31;   // output feature

    float z = bias[g];
#pragma unroll
    for (int u = 0; u < 64; ++u)
        z += sacc[n * 64 + u] * swp[u * 32 + g];
    z = fmaxf(z, 0.f);

    // LayerNorm over the 32 features of this node (lanes g=0..31 of each half-wave)
    float s1 = z, s2 = z * z;
#pragma unroll
    for (int m = 16; m >= 1; m >>= 1) {
        s1 += __shfl_xor(s1, m, 32);
        s2 += __shfl_xor(s2, m, 32);
    }
    float mu  = s1 * (1.f / 32.f);
    float var = s2 * (1.f / 32.f) - mu * mu;
    float v = (z - mu) * rsqrtf(var + 1e-6f) * gamma[g] + beta[g];

    int gn = n0 + n;
    if (RESIDUAL) v += resid[gn * FF + g];
    out[gn * FF + g] = v;
}

extern "C" void kernel_launch(void* const* d_in, const int* in_sizes, int n_in,
                              void* d_out, int out_size, void* d_ws, size_t ws_size,
                              hipStream_t stream) {
    const float* maps  = (const float*)d_in[0];
    const int*   idx1  = (const int*)  d_in[1];
    const float* w1nb  = (const float*)d_in[2];
    const int*   idx2  = (const int*)  d_in[3];
    const float* w2nb  = (const float*)d_in[4];
    const float* wd1   = (const float*)d_in[5];
    const float* wp1   = (const float*)d_in[6];
    const float* b1    = (const float*)d_in[7];
    const float* g1    = (const float*)d_in[8];
    const float* be1   = (const float*)d_in[9];
    const float* wd2   = (const float*)d_in[10];
    const float* wp2   = (const float*)d_in[11];
    const float* b2    = (const float*)d_in[12];
    const float* g2    = (const float*)d_in[13];
    const float* be2   = (const float*)d_in[14];
    float* out = (float*)d_out;

    float* ws   = (float*)d_ws;
    float* bufA = ws;                                  // N*32
    float* bufB = ws + (size_t)NPIX * FF;              // N*32
    float* acc  = ws + (size_t)2 * NPIX * FF;          // N*64
    float* x1   = ws + (size_t)2 * NPIX * FF + (size_t)NPIX * 64;  // N*32

    const int nodeBlocks = NPIX * FF / 256;   // 24576, thread per (n,f)
    const int finBlocks  = NPIX / 8;          // 24576, 8 nodes per block

    // ---------------- layer 1: K=6, NB=8 ----------------
    cheb_init_kernel<8><<<nodeBlocks, 256, 0, stream>>>(maps, idx1, w1nb, wd1, bufA, acc);
    // k=2: T2 = 2 L(T1) - T0(maps) -> bufB
    cheb_step_kernel<8><<<nodeBlocks, 256, 0, stream>>>(bufA, maps, bufB, idx1, w1nb, wd1, 2, acc);
    cheb_step_kernel<8><<<nodeBlocks, 256, 0, stream>>>(bufB, bufA, bufA, idx1, w1nb, wd1, 3, acc);
    cheb_step_kernel<8><<<nodeBlocks, 256, 0, stream>>>(bufA, bufB, bufB, idx1, w1nb, wd1, 4, acc);
    cheb_step_kernel<8><<<nodeBlocks, 256, 0, stream>>>(bufB, bufA, bufA, idx1, w1nb, wd1, 5, acc);
    finish_kernel<false><<<finBlocks, 256, 0, stream>>>(acc, wp1, b1, g1, be1, nullptr, x1);

    // ---------------- layer 2: K=10, NB=20 ----------------
    cheb_init_kernel<20><<<nodeBlocks, 256, 0, stream>>>(x1, idx2, w2nb, wd2, bufA, acc);
    cheb_step_kernel<20><<<nodeBlocks, 256, 0, stream>>>(bufA, x1, bufB, idx2, w2nb, wd2, 2, acc);
    cheb_step_kernel<20><<<nodeBlocks, 256, 0, stream>>>(bufB, bufA, bufA, idx2, w2nb, wd2, 3, acc);
    cheb_step_kernel<20><<<nodeBlocks, 256, 0, stream>>>(bufA, bufB, bufB, idx2, w2nb, wd2, 4, acc);
    cheb_step_kernel<20><<<nodeBlocks, 256, 0, stream>>>(bufB, bufA, bufA, idx2, w2nb, wd2, 5, acc);
    cheb_step_kernel<20><<<nodeBlocks, 256, 0, stream>>>(bufA, bufB, bufB, idx2, w2nb, wd2, 6, acc);
    cheb_step_kernel<20><<<nodeBlocks, 256, 0, stream>>>(bufB, bufA, bufA, idx2, w2nb, wd2, 7, acc);
    cheb_step_kernel<20><<<nodeBlocks, 256, 0, stream>>>(bufA, bufB, bufB, idx2, w2nb, wd2, 8, acc);
    cheb_step_kernel<20><<<nodeBlocks, 256, 0, stream>>>(bufB, bufA, bufA, idx2, w2nb, wd2, 9, acc);
    finish_kernel<true><<<finBlocks, 256, 0, stream>>>(acc, wp2, b2, g2, be2, maps, out);
}

// Round 2
// 767.143 us; speedup vs baseline: 1.4637x; 1.4637x over previous
//
#include <hip/hip_runtime.h>

constexpr int NPIX = 196608;
constexpr int FF   = 32;                       // features
constexpr size_t SLOT = (size_t)NPIX * FF;     // elems per T buffer

__device__ __forceinline__ float b2f(ushort u) {
    union { float f; unsigned int i; } v; v.i = ((unsigned int)u) << 16; return v.f;
}
__device__ __forceinline__ ushort f2b(float f) {
    union { float f; unsigned int i; } v; v.f = f;
    unsigned int r = v.i + 0x7fffu + ((v.i >> 16) & 1u);   // round-to-nearest-even
    return (ushort)(r >> 16);
}

// ---------------- fp32 -> bf16 convert (maps -> chain T0) ----------------
__global__ __launch_bounds__(256) void f2b_kernel(const float* __restrict__ src,
                                                  ushort* __restrict__ dst) {
    int i = (blockIdx.x * 256 + threadIdx.x) * 4;
    float4 v = *reinterpret_cast<const float4*>(src + i);
    ushort4 o;
    o.x = f2b(v.x); o.y = f2b(v.y); o.z = f2b(v.z); o.w = f2b(v.w);
    *reinterpret_cast<ushort4*>(dst + i) = o;
}

// ---------------- T1 = L(T0) ----------------
template<int NB>
__global__ __launch_bounds__(256) void cheb_init_kernel(
    const ushort* __restrict__ Tprev,
    const int*    __restrict__ idx,
    const float*  __restrict__ wnb,
    ushort*       __restrict__ Tout)
{
    int t = blockIdx.x * 256 + threadIdx.x;
    int n = t >> 5;
    int f = t & 31;
    const int4*   ip  = reinterpret_cast<const int4*>(idx + (size_t)n * NB);
    const float4* wp4 = reinterpret_cast<const float4*>(wnb + (size_t)n * NB);
    float s = 0.f;
#pragma unroll
    for (int j4 = 0; j4 < NB / 4; ++j4) {
        int4   i4 = ip[j4];
        float4 w4 = wp4[j4];
        s += w4.x * b2f(Tprev[(size_t)i4.x * FF + f]);
        s += w4.y * b2f(Tprev[(size_t)i4.y * FF + f]);
        s += w4.z * b2f(Tprev[(size_t)i4.z * FF + f]);
        s += w4.w * b2f(Tprev[(size_t)i4.w * FF + f]);
    }
    Tout[(size_t)n * FF + f] = f2b(s);
}

// ---------------- T_k = 2 L(T_{k-1}) - T_{k-2} ----------------
template<int NB>
__global__ __launch_bounds__(256) void cheb_step_kernel(
    const ushort* __restrict__ Tprev,
    const ushort* __restrict__ Told,
    ushort*       __restrict__ Tout,
    const int*    __restrict__ idx,
    const float*  __restrict__ wnb)
{
    int t = blockIdx.x * 256 + threadIdx.x;
    int n = t >> 5;
    int f = t & 31;
    const int4*   ip  = reinterpret_cast<const int4*>(idx + (size_t)n * NB);
    const float4* wp4 = reinterpret_cast<const float4*>(wnb + (size_t)n * NB);
    float s = 0.f;
#pragma unroll
    for (int j4 = 0; j4 < NB / 4; ++j4) {
        int4   i4 = ip[j4];
        float4 w4 = wp4[j4];
        s += w4.x * b2f(Tprev[(size_t)i4.x * FF + f]);
        s += w4.y * b2f(Tprev[(size_t)i4.y * FF + f]);
        s += w4.z * b2f(Tprev[(size_t)i4.z * FF + f]);
        s += w4.w * b2f(Tprev[(size_t)i4.w * FF + f]);
    }
    size_t base = (size_t)n * FF + f;
    Tout[base] = f2b(2.f * s - b2f(Told[base]));
}

// ----- finish: acc[k-fold] -> @wp + b -> relu -> layernorm -> (+residual) -----
template<int K, bool RESIDUAL, bool OUT_BF16>
__global__ __launch_bounds__(256) void finish_kernel(
    const ushort* __restrict__ chain,  // K contiguous bf16 [N][32] buffers
    const float*  __restrict__ wd,     // [K][32][2]
    const float*  __restrict__ wp,     // [64][32]
    const float*  __restrict__ bias,
    const float*  __restrict__ gamma,
    const float*  __restrict__ beta,
    const float*  __restrict__ resid,  // fp32 maps or nullptr
    void*         __restrict__ outp)   // bf16 (ushort*) or fp32 (float*)
{
    __shared__ float swp[64 * 32];
    __shared__ float sacc[8 * 64];

    int tid = threadIdx.x;
    for (int i = tid; i < 64 * 32; i += 256) swp[i] = wp[i];

    int n  = tid >> 5;             // node within block (0..7)
    int f  = tid & 31;
    int n0 = blockIdx.x * 8;
    size_t base = (size_t)(n0 + n) * FF + f;

    float a0 = 0.f, a1 = 0.f;
#pragma unroll
    for (int k = 0; k < K; ++k) {
        float tv = b2f(chain[(size_t)k * SLOT + base]);
        float2 w = *reinterpret_cast<const float2*>(wd + (k * FF + f) * 2);
        a0 += tv * w.x;
        a1 += tv * w.y;
    }
    sacc[n * 64 + f * 2]     = a0;
    sacc[n * 64 + f * 2 + 1] = a1;
    __syncthreads();

    float z = bias[f];
#pragma unroll
    for (int u = 0; u < 64; ++u)
        z += sacc[n * 64 + u] * swp[u * 32 + f];
    z = fmaxf(z, 0.f);

    float s1 = z, s2 = z * z;
#pragma unroll
    for (int m = 16; m >= 1; m >>= 1) {
        s1 += __shfl_xor(s1, m, 32);
        s2 += __shfl_xor(s2, m, 32);
    }
    float mu  = s1 * (1.f / 32.f);
    float var = s2 * (1.f / 32.f) - mu * mu;
    float v = (z - mu) * rsqrtf(var + 1e-6f) * gamma[f] + beta[f];
    if (RESIDUAL) v += resid[base];

    if (OUT_BF16) ((ushort*)outp)[base] = f2b(v);
    else          ((float*)outp)[base]  = v;
}

extern "C" void kernel_launch(void* const* d_in, const int* in_sizes, int n_in,
                              void* d_out, int out_size, void* d_ws, size_t ws_size,
                              hipStream_t stream) {
    const float* maps = (const float*)d_in[0];
    const int*   idx1 = (const int*)  d_in[1];
    const float* w1nb = (const float*)d_in[2];
    const int*   idx2 = (const int*)  d_in[3];
    const float* w2nb = (const float*)d_in[4];
    const float* wd1  = (const float*)d_in[5];
    const float* wp1  = (const float*)d_in[6];
    const float* b1   = (const float*)d_in[7];
    const float* g1   = (const float*)d_in[8];
    const float* be1  = (const float*)d_in[9];
    const float* wd2  = (const float*)d_in[10];
    const float* wp2  = (const float*)d_in[11];
    const float* b2   = (const float*)d_in[12];
    const float* g2   = (const float*)d_in[13];
    const float* be2  = (const float*)d_in[14];
    float* out = (float*)d_out;

    // ws layout: 10 bf16 slots. Layer-2 chain B0..B9 = slots 0..9 (contiguous).
    // Layer-1 chain A0..A5 = slots 4..9 (contiguous); overwritten as B4..B9
    // only after finish1 has consumed them.
    ushort* slots = (ushort*)d_ws;
    ushort* B = slots;               // B0..B9
    ushort* A = slots + 4 * SLOT;    // A0..A5

    const int nodeBlocks = NPIX * FF / 256;      // 24576
    const int cvtBlocks  = NPIX * FF / (256*4);  // 6144
    const int finBlocks  = NPIX / 8;             // 24576

    // ---------------- layer 1: K=6, NB=8 ----------------
    f2b_kernel<<<cvtBlocks, 256, 0, stream>>>(maps, A);                     // A0
    cheb_init_kernel<8><<<nodeBlocks, 256, 0, stream>>>(A, idx1, w1nb, A + SLOT);  // A1
    cheb_step_kernel<8><<<nodeBlocks, 256, 0, stream>>>(A + SLOT,   A,          A + 2*SLOT, idx1, w1nb);
    cheb_step_kernel<8><<<nodeBlocks, 256, 0, stream>>>(A + 2*SLOT, A + SLOT,   A + 3*SLOT, idx1, w1nb);
    cheb_step_kernel<8><<<nodeBlocks, 256, 0, stream>>>(A + 3*SLOT, A + 2*SLOT, A + 4*SLOT, idx1, w1nb);
    cheb_step_kernel<8><<<nodeBlocks, 256, 0, stream>>>(A + 4*SLOT, A + 3*SLOT, A + 5*SLOT, idx1, w1nb);
    finish_kernel<6, false, true><<<finBlocks, 256, 0, stream>>>(A, wd1, wp1, b1, g1, be1, nullptr, B);  // -> B0 (x1 bf16)

    // ---------------- layer 2: K=10, NB=20 ----------------
    cheb_init_kernel<20><<<nodeBlocks, 256, 0, stream>>>(B, idx2, w2nb, B + SLOT); // B1
    for (int k = 2; k <= 9; ++k)
        cheb_step_kernel<20><<<nodeBlocks, 256, 0, stream>>>(
            B + (size_t)(k-1)*SLOT, B + (size_t)(k-2)*SLOT, B + (size_t)k*SLOT, idx2, w2nb);
    finish_kernel<10, true, false><<<finBlocks, 256, 0, stream>>>(B, wd2, wp2, b2, g2, be2, maps, out);
}

// Round 3
// 733.726 us; speedup vs baseline: 1.5303x; 1.0455x over previous
//
#include <hip/hip_runtime.h>

constexpr int NPIX = 196608;
constexpr int FF   = 32;
constexpr size_t SLOT = (size_t)NPIX * FF;

typedef short bf16x8 __attribute__((ext_vector_type(8)));
typedef float f32x4  __attribute__((ext_vector_type(4)));

__device__ __forceinline__ float b2f(ushort u) {
    union { float f; unsigned int i; } v; v.i = ((unsigned int)u) << 16; return v.f;
}
__device__ __forceinline__ ushort f2b(float f) {
    union { float f; unsigned int i; } v; v.f = f;
    unsigned int r = v.i + 0x7fffu + ((v.i >> 16) & 1u);   // RNE
    return (ushort)(r >> 16);
}

// ---------------- fp32 -> bf16 convert (maps -> chain T0) ----------------
__global__ __launch_bounds__(256) void f2b_kernel(const float* __restrict__ src,
                                                  ushort* __restrict__ dst) {
    int i = (blockIdx.x * 256 + threadIdx.x) * 4;
    float4 v = *reinterpret_cast<const float4*>(src + i);
    ushort4 o;
    o.x = f2b(v.x); o.y = f2b(v.y); o.z = f2b(v.z); o.w = f2b(v.w);
    *reinterpret_cast<ushort4*>(dst + i) = o;
}

// ---------------- T1 = L(T0), 2 features per thread ----------------
template<int NB>
__global__ __launch_bounds__(256) void cheb_init2(
    const ushort* __restrict__ Tprev,
    const int*    __restrict__ idx,
    const float*  __restrict__ wnb,
    ushort*       __restrict__ Tout)
{
    int t = blockIdx.x * 256 + threadIdx.x;
    int n = t >> 4;
    int h = t & 15;
    const uint*   Tp  = reinterpret_cast<const uint*>(Tprev);
    const int4*   ip  = reinterpret_cast<const int4*>(idx + (size_t)n * NB);
    const float4* wp4 = reinterpret_cast<const float4*>(wnb + (size_t)n * NB);
    float s0 = 0.f, s1 = 0.f;
#pragma unroll
    for (int j4 = 0; j4 < NB / 4; ++j4) {
        int4   i4 = ip[j4];
        float4 w4 = wp4[j4];
        uint u;
        u = Tp[(size_t)i4.x * 16 + h]; s0 += w4.x * b2f((ushort)u); s1 += w4.x * b2f((ushort)(u >> 16));
        u = Tp[(size_t)i4.y * 16 + h]; s0 += w4.y * b2f((ushort)u); s1 += w4.y * b2f((ushort)(u >> 16));
        u = Tp[(size_t)i4.z * 16 + h]; s0 += w4.z * b2f((ushort)u); s1 += w4.z * b2f((ushort)(u >> 16));
        u = Tp[(size_t)i4.w * 16 + h]; s0 += w4.w * b2f((ushort)u); s1 += w4.w * b2f((ushort)(u >> 16));
    }
    reinterpret_cast<uint*>(Tout)[(size_t)n * 16 + h] =
        ((uint)f2b(s1) << 16) | (uint)f2b(s0);
}

// ---------------- T_k = 2 L(T_{k-1}) - T_{k-2}, 2 features per thread ----------------
template<int NB>
__global__ __launch_bounds__(256) void cheb_step2(
    const ushort* __restrict__ Tprev,
    const ushort* __restrict__ Told,
    ushort*       __restrict__ Tout,
    const int*    __restrict__ idx,
    const float*  __restrict__ wnb)
{
    int t = blockIdx.x * 256 + threadIdx.x;
    int n = t >> 4;
    int h = t & 15;
    const uint*   Tp  = reinterpret_cast<const uint*>(Tprev);
    const int4*   ip  = reinterpret_cast<const int4*>(idx + (size_t)n * NB);
    const float4* wp4 = reinterpret_cast<const float4*>(wnb + (size_t)n * NB);
    float s0 = 0.f, s1 = 0.f;
#pragma unroll
    for (int j4 = 0; j4 < NB / 4; ++j4) {
        int4   i4 = ip[j4];
        float4 w4 = wp4[j4];
        uint u;
        u = Tp[(size_t)i4.x * 16 + h]; s0 += w4.x * b2f((ushort)u); s1 += w4.x * b2f((ushort)(u >> 16));
        u = Tp[(size_t)i4.y * 16 + h]; s0 += w4.y * b2f((ushort)u); s1 += w4.y * b2f((ushort)(u >> 16));
        u = Tp[(size_t)i4.z * 16 + h]; s0 += w4.z * b2f((ushort)u); s1 += w4.z * b2f((ushort)(u >> 16));
        u = Tp[(size_t)i4.w * 16 + h]; s0 += w4.w * b2f((ushort)u); s1 += w4.w * b2f((ushort)(u >> 16));
    }
    size_t base = (size_t)n * 16 + h;
    uint to = reinterpret_cast<const uint*>(Told)[base];
    float t0 = 2.f * s0 - b2f((ushort)to);
    float t1 = 2.f * s1 - b2f((ushort)(to >> 16));
    reinterpret_cast<uint*>(Tout)[base] = ((uint)f2b(t1) << 16) | (uint)f2b(t0);
}

// ----- finish (MFMA): fold chain -> [N,64] bf16; MFMA @wp; relu; LN; (+resid) -----
template<int K, bool RESIDUAL, bool OUT_BF16>
__global__ __launch_bounds__(256) void finish_mfma(
    const ushort* __restrict__ chain,  // K contiguous bf16 [N][32] buffers
    const float*  __restrict__ wd,     // [K][32][2]
    const float*  __restrict__ wp,     // [64][32]
    const float*  __restrict__ bias,
    const float*  __restrict__ gamma,
    const float*  __restrict__ beta,
    const float*  __restrict__ resid,  // fp32 maps or nullptr
    void*         __restrict__ outp)   // ushort* (bf16) or float*
{
    // row stride 72 ushorts = 144 B (16B-aligned, breaks 128B bank pattern)
    __shared__ __align__(16) ushort sA[4][16][72];   // per-wave [node][u]
    __shared__ __align__(16) ushort sB[32][72];      // wp transposed: [g][u]

    int tid = threadIdx.x;
    int w = tid >> 6;
    int l = tid & 63;

    // stage wp -> sB (bf16, transposed), once per block
    for (int i = tid; i < 64 * 32; i += 256) {
        int u = i >> 5, g = i & 31;
        sB[g][u] = f2b(wp[i]);
    }

    int nbase = blockIdx.x * 64 + w * 16;

    // fold: acc[n][u=2f+d] = sum_k T_k[n][f] * wd[k][f][d]  (fp32, then bf16 pack)
#pragma unroll
    for (int p = 0; p < 8; ++p) {
        int flat = p * 64 + l;
        int nloc = flat >> 5;
        int f    = flat & 31;
        size_t base = (size_t)(nbase + nloc) * FF + f;
        float a0 = 0.f, a1 = 0.f;
#pragma unroll
        for (int k = 0; k < K; ++k) {
            float tv = b2f(chain[(size_t)k * SLOT + base]);
            float2 wk = *reinterpret_cast<const float2*>(wd + (k * FF + f) * 2);
            a0 += tv * wk.x;
            a1 += tv * wk.y;
        }
        uint packed = ((uint)f2b(a1) << 16) | (uint)f2b(a0);
        reinterpret_cast<uint*>(&sA[w][nloc][0])[f] = packed;
    }
    __syncthreads();

    // MFMA: D[16 nodes, 32 g] = A[16,64] @ B[64,32], two 16-wide g tiles
    f32x4 acc0 = {0.f, 0.f, 0.f, 0.f};
    f32x4 acc1 = {0.f, 0.f, 0.f, 0.f};
    int r  = l & 15;
    int ko = (l >> 4) * 8;
#pragma unroll
    for (int kt = 0; kt < 2; ++kt) {
        bf16x8 aF = *reinterpret_cast<const bf16x8*>(&sA[w][r][kt * 32 + ko]);
        bf16x8 b0 = *reinterpret_cast<const bf16x8*>(&sB[r][kt * 32 + ko]);
        bf16x8 b1 = *reinterpret_cast<const bf16x8*>(&sB[16 + r][kt * 32 + ko]);
        acc0 = __builtin_amdgcn_mfma_f32_16x16x32_bf16(aF, b0, acc0, 0, 0, 0);
        acc1 = __builtin_amdgcn_mfma_f32_16x16x32_bf16(aF, b1, acc1, 0, 0, 0);
    }

    // epilogue: bias+relu, LN over 32 g (16-lane groups hold one node per acc reg)
    float bias_lo = bias[r],  bias_hi = bias[16 + r];
    float gam_lo  = gamma[r], gam_hi  = gamma[16 + r];
    float bet_lo  = beta[r],  bet_hi  = beta[16 + r];

#pragma unroll
    for (int v = 0; v < 4; ++v) {
        acc0[v] = fmaxf(acc0[v] + bias_lo, 0.f);
        acc1[v] = fmaxf(acc1[v] + bias_hi, 0.f);
    }
#pragma unroll
    for (int v = 0; v < 4; ++v) {
        float s1 = acc0[v] + acc1[v];
        float s2 = acc0[v] * acc0[v] + acc1[v] * acc1[v];
#pragma unroll
        for (int m = 1; m < 16; m <<= 1) {
            s1 += __shfl_xor(s1, m);
            s2 += __shfl_xor(s2, m);
        }
        float mu  = s1 * (1.f / 32.f);
        float var = s2 * (1.f / 32.f) - mu * mu;
        float rs  = rsqrtf(var + 1e-6f);
        int n = nbase + (l >> 4) * 4 + v;
        size_t o0 = (size_t)n * FF + r;
        size_t o1 = o0 + 16;
        float z0 = (acc0[v] - mu) * rs * gam_lo + bet_lo;
        float z1 = (acc1[v] - mu) * rs * gam_hi + bet_hi;
        if (RESIDUAL) { z0 += resid[o0]; z1 += resid[o1]; }
        if (OUT_BF16) {
            ((ushort*)outp)[o0] = f2b(z0);
            ((ushort*)outp)[o1] = f2b(z1);
        } else {
            ((float*)outp)[o0] = z0;
            ((float*)outp)[o1] = z1;
        }
    }
}

extern "C" void kernel_launch(void* const* d_in, const int* in_sizes, int n_in,
                              void* d_out, int out_size, void* d_ws, size_t ws_size,
                              hipStream_t stream) {
    const float* maps = (const float*)d_in[0];
    const int*   idx1 = (const int*)  d_in[1];
    const float* w1nb = (const float*)d_in[2];
    const int*   idx2 = (const int*)  d_in[3];
    const float* w2nb = (const float*)d_in[4];
    const float* wd1  = (const float*)d_in[5];
    const float* wp1  = (const float*)d_in[6];
    const float* b1   = (const float*)d_in[7];
    const float* g1   = (const float*)d_in[8];
    const float* be1  = (const float*)d_in[9];
    const float* wd2  = (const float*)d_in[10];
    const float* wp2  = (const float*)d_in[11];
    const float* b2   = (const float*)d_in[12];
    const float* g2   = (const float*)d_in[13];
    const float* be2  = (const float*)d_in[14];
    float* out = (float*)d_out;

    // ws: 10 bf16 slots. Layer-2 chain B0..B9 = slots 0..9; layer-1 chain
    // A0..A5 = slots 4..9 (consumed by finish1 before B4..B9 overwrite them).
    ushort* slots = (ushort*)d_ws;
    ushort* B = slots;
    ushort* A = slots + 4 * SLOT;

    const int stepBlocks = NPIX * 16 / 256;       // 12288
    const int cvtBlocks  = NPIX * FF / (256 * 4); // 6144
    const int finBlocks  = NPIX / 64;             // 3072

    // ---------------- layer 1: K=6, NB=8 ----------------
    f2b_kernel<<<cvtBlocks, 256, 0, stream>>>(maps, A);                          // A0
    cheb_init2<8><<<stepBlocks, 256, 0, stream>>>(A, idx1, w1nb, A + SLOT);      // A1
    cheb_step2<8><<<stepBlocks, 256, 0, stream>>>(A + SLOT,     A,              A + 2 * SLOT, idx1, w1nb);
    cheb_step2<8><<<stepBlocks, 256, 0, stream>>>(A + 2 * SLOT, A + SLOT,       A + 3 * SLOT, idx1, w1nb);
    cheb_step2<8><<<stepBlocks, 256, 0, stream>>>(A + 3 * SLOT, A + 2 * SLOT,   A + 4 * SLOT, idx1, w1nb);
    cheb_step2<8><<<stepBlocks, 256, 0, stream>>>(A + 4 * SLOT, A + 3 * SLOT,   A + 5 * SLOT, idx1, w1nb);
    finish_mfma<6, false, true><<<finBlocks, 256, 0, stream>>>(A, wd1, wp1, b1, g1, be1, nullptr, B);  // -> B0

    // ---------------- layer 2: K=10, NB=20 ----------------
    cheb_init2<20><<<stepBlocks, 256, 0, stream>>>(B, idx2, w2nb, B + SLOT);     // B1
    for (int k = 2; k <= 9; ++k)
        cheb_step2<20><<<stepBlocks, 256, 0, stream>>>(
            B + (size_t)(k - 1) * SLOT, B + (size_t)(k - 2) * SLOT,
            B + (size_t)k * SLOT, idx2, w2nb);
    finish_mfma<10, true, false><<<finBlocks, 256, 0, stream>>>(B, wd2, wp2, b2, g2, be2, maps, out);
}